// Round 1
// baseline (8492.835 us; speedup 1.0000x reference)
//
#include <hip/hip_runtime.h>
#include <stdint.h>

typedef unsigned short u16;
typedef __attribute__((ext_vector_type(8))) short bf16x8;
typedef __attribute__((ext_vector_type(4))) float f32x4;

#define T_STEPS 512
#define BATCH   64
#define HID     1024
#define NWG_SCAN 64

__device__ __forceinline__ u16 f2bf(float f) {
  union { float f; uint32_t u; } v; v.f = f;
  uint32_t r = (v.u + 0x7fffu + ((v.u >> 16) & 1u)) >> 16;  // RNE
  return (u16)r;
}
__device__ __forceinline__ float bf2f(u16 h) {
  union { uint32_t u; float f; } v; v.u = ((uint32_t)h) << 16;
  return v.f;
}
__device__ __forceinline__ float sigmoidf_(float x) {
  return 1.0f / (1.0f + __expf(-x));
}
// fast tanh via exp2-based __expf; clamped so e^{2x} can't overflow.
// bf16 state quantization (~4e-3 rel) dominates the ~1e-7 approx error.
__device__ __forceinline__ float fast_tanhf(float x) {
  float xc = fminf(15.f, fmaxf(-15.f, x));
  float e = __expf(2.f * xc);
  return (e - 1.f) / (e + 1.f);
}

// write-through store (sc1): visible at LLC once vmcnt acks -> no buffer_wbl2
// needed at the grid barrier. Local XCD L2 stays coherent with its own store.
__device__ __forceinline__ void store_bf16_sc1(u16* p, u16 v) {
  uint32_t vv = v;
  asm volatile("global_store_short %0, %1, off sc1" :: "v"(p), "v"(vv) : "memory");
}

// ---------------------------------------------------------------------------
// Transpose + cast: dst[n][k] = bf16(src[k][n]), 1024x1024
// ---------------------------------------------------------------------------
__global__ __launch_bounds__(256) void transpose_cast(const float* __restrict__ src,
                                                      u16* __restrict__ dst) {
  __shared__ float tile[32][33];
  int bx = blockIdx.x * 32;  // k block (src row)
  int by = blockIdx.y * 32;  // n block (src col)
  for (int i = threadIdx.y; i < 32; i += 8)
    tile[i][threadIdx.x] = src[(size_t)(bx + i) * 1024 + by + threadIdx.x];
  __syncthreads();
  for (int i = threadIdx.y; i < 32; i += 8)
    dst[(size_t)(by + i) * 1024 + bx + threadIdx.x] = f2bf(tile[threadIdx.x][i]);
}

// bias3 = concat(b_r, b_u, b_h)
__global__ void concat_bias(const float* __restrict__ br, const float* __restrict__ bu,
                            const float* __restrict__ bh, float* __restrict__ b3) {
  int i = blockIdx.x * blockDim.x + threadIdx.x;  // 0..3071
  float v = (i < 1024) ? br[i] : (i < 2048 ? bu[i - 1024] : bh[i - 2048]);
  b3[i] = v;
}

// ---------------------------------------------------------------------------
// GEMM: C[M,N] = A[M,K] @ B[K,N] + bias, B given transposed (BT[N][K]).
// 128x128 tile, BK=32, 256 thr, mfma 16x16x32 bf16, XOR-swizzled LDS.
// ---------------------------------------------------------------------------
template <int A_F32, int OUT_BF16>
__global__ __launch_bounds__(256) void gemm_bt(const void* __restrict__ Av,
                                               const u16* __restrict__ BT,
                                               const float* __restrict__ bias,
                                               void* __restrict__ Cv,
                                               int M, int N, int K) {
  __shared__ u16 Asm[4096];
  __shared__ u16 Bsm[4096];
  const int tid = threadIdx.x;
  const int lane = tid & 63;
  const int wv = tid >> 6;
  const int wm = wv >> 1, wn = wv & 1;
  const int m0 = blockIdx.x * 128;
  const int n0 = blockIdx.y * 128;

  f32x4 acc[4][4];
#pragma unroll
  for (int i = 0; i < 4; i++)
#pragma unroll
    for (int j = 0; j < 4; j++) acc[i][j] = (f32x4){0.f, 0.f, 0.f, 0.f};

  for (int kt = 0; kt < K; kt += 32) {
    __syncthreads();
#pragma unroll
    for (int i = 0; i < 2; i++) {
      int q = tid + i * 256;
      int m = q >> 2, s = q & 3;
      int bb = s ^ ((m & 3) ^ ((m >> 2) & 3));
      if (A_F32) {
        const float* srcp = (const float*)Av + (size_t)(m0 + m) * K + kt + bb * 8;
        bf16x8 o;
#pragma unroll
        for (int e = 0; e < 8; e++) o[e] = (short)f2bf(srcp[e]);
        *(bf16x8*)&Asm[q * 8] = o;
      } else {
        const u16* srcp = (const u16*)Av + (size_t)(m0 + m) * K + kt + bb * 8;
        *(bf16x8*)&Asm[q * 8] = *(const bf16x8*)srcp;
      }
      const u16* srcb = BT + (size_t)(n0 + m) * K + kt + bb * 8;
      *(bf16x8*)&Bsm[q * 8] = *(const bf16x8*)srcb;
    }
    __syncthreads();

    bf16x8 af[4], bfr[4];
    int bb = lane >> 4;
#pragma unroll
    for (int mt = 0; mt < 4; mt++) {
      int m = wm * 64 + mt * 16 + (lane & 15);
      int s = bb ^ ((m & 3) ^ ((m >> 2) & 3));
      af[mt] = *(const bf16x8*)&Asm[m * 32 + s * 8];
    }
#pragma unroll
    for (int nt = 0; nt < 4; nt++) {
      int n = wn * 64 + nt * 16 + (lane & 15);
      int s = bb ^ ((n & 3) ^ ((n >> 2) & 3));
      bfr[nt] = *(const bf16x8*)&Bsm[n * 32 + s * 8];
    }
#pragma unroll
    for (int mt = 0; mt < 4; mt++)
#pragma unroll
      for (int nt = 0; nt < 4; nt++)
        acc[mt][nt] = __builtin_amdgcn_mfma_f32_16x16x32_bf16(af[mt], bfr[nt], acc[mt][nt], 0, 0, 0);
  }

#pragma unroll
  for (int nt = 0; nt < 4; nt++) {
    int col = n0 + wn * 64 + nt * 16 + (lane & 15);
    float bv = bias[col];
#pragma unroll
    for (int mt = 0; mt < 4; mt++) {
#pragma unroll
      for (int r = 0; r < 4; r++) {
        int row = m0 + wm * 64 + mt * 16 + (lane >> 4) * 4 + r;
        float v = acc[mt][nt][r] + bv;
        if (OUT_BF16)
          ((u16*)Cv)[(size_t)row * N + col] = f2bf(v);
        else
          ((float*)Cv)[(size_t)row * N + col] = v;
      }
    }
  }
}

// ---------------------------------------------------------------------------
// Persistent GRU scan, 64 WGs x 256 thr (1 WG/CU, 96KB LDS).
// Each WG owns cols j = wg*16..wg*16+15 of ALL THREE recurrent matrices.
// pass1: R-gate + U-gate GEMMs (shared A-fragments from SB[t], loaded once).
//        Writes A2 = bf16(R*s_prev) with sc1 stores OVERLAYED onto Xproj's
//        r-region for step t (dead data, rotating addresses -> no stale-L2).
//        U and s_prev stay in REGISTERS (s_prev is carried from pass2 of the
//        previous step: identical (b,j)->thread mapping in both passes).
// pass2: Hc GEMM over A2-overlay + state update; SB[t+1] via sc1; fp32
//        out_states stores deferred to AFTER barrier arrival (ack overlaps
//        the spin instead of the pre-barrier drain).
// Grid barrier: vmcnt(0) drain -> syncthreads -> 1 atomic/WG -> all-wave spin.
// ---------------------------------------------------------------------------
__global__ __launch_bounds__(256, 1) void gru_scan(const float* __restrict__ W_hr,
                                                   const float* __restrict__ W_hu,
                                                   const float* __restrict__ W_hh,
                                                   u16* __restrict__ Xproj,        // [T*B][3072] bf16 (r-region mutated)
                                                   u16* __restrict__ SB,           // [T+1][B][H] bf16
                                                   float* __restrict__ out_states, // [T*B][H] fp32
                                                   unsigned* __restrict__ bar) {
  __shared__ u16 lds[49152];  // 96KB: [0:16K)=W_hr slice, [16K:32K)=W_hu, [32K:48K)=W_hh
  const int tid = threadIdx.x;
  const int lane = tid & 63;
  const int wv = tid >> 6;
  const int wg = blockIdx.x;  // 0..63

  // ---- one-time LDS weight fill: 1024x16 slice of each matrix, swizzled ----
  {
    const int cbase = wg * 16;
#pragma unroll
    for (int s = 0; s < 3; s++) {
      const float* Wsrc = (s == 0) ? W_hr : (s == 1) ? W_hu : W_hh;
      for (int idx = tid; idx < 16384; idx += 256) {
        int kin = idx & 31, nl_ = (idx >> 5) & 15, kb = idx >> 9;
        float v = Wsrc[(size_t)(kb * 32 + kin) * 1024 + cbase + nl_];
        int slot_ = (kin >> 3) ^ (nl_ & 3) ^ ((nl_ >> 2) & 3);
        lds[s * 16384 + ((kb * 16 + nl_) * 4 + slot_) * 8 + (kin & 7)] = f2bf(v);
      }
    }
  }
  __syncthreads();

  unsigned phase = 0;
  const int bb = lane >> 4;
  const int nl = lane & 15;
  const int quad = lane >> 4;
  const int slot = bb ^ ((nl & 3) ^ ((nl >> 2) & 3));
  const int rt = wv;            // wave's 16-row block of the 64 batch rows
  const int j = wg * 16 + nl;   // this thread's output column

  float Ureg[4];
  float Sreg[4] = {0.f, 0.f, 0.f, 0.f};  // s_t(b_,j), carried across steps; s_0 = 0

  for (int t = 0; t < T_STEPS; t++) {
    const u16* SBt = SB + (size_t)t * BATCH * HID;
    u16* A2 = Xproj + (size_t)t * 64 * 3072;  // r-region overlay, row stride 3072

    // ================= pass1: R and U gate GEMMs =================
    {
      // A-fragments: full state rows (loaded ONCE, used for both gates)
      const u16* abase = SBt + (size_t)(rt * 16 + nl) * HID + bb * 8;
      bf16x8 af[32];
#pragma unroll
      for (int kb = 0; kb < 32; kb++) af[kb] = *(const bf16x8*)(abase + kb * 32);

      // early scalar loads (hide HBM/LLC latency under the MFMA chain)
      float xr[4], xu[4];
      u16* xaddr[4];
#pragma unroll
      for (int r = 0; r < 4; r++) {
        int b_ = rt * 16 + quad * 4 + r;
        xaddr[r] = A2 + (size_t)b_ * 3072 + j;
        xr[r] = bf2f(*xaddr[r]);
        xu[r] = bf2f(Xproj[(size_t)(t * 64 + b_) * 3072 + 1024 + j]);
      }

      // 64 MFMAs in 4 independent chains (r0,u0,r1,u1)
      f32x4 ar0 = (f32x4){0.f, 0.f, 0.f, 0.f}, ar1 = ar0, au0 = ar0, au1 = ar0;
      const u16* lbr = &lds[(nl * 4 + slot) * 8];
#pragma unroll
      for (int kb = 0; kb < 32; kb += 2) {
        bf16x8 br0 = *(const bf16x8*)(lbr + kb * 512);
        bf16x8 bu0 = *(const bf16x8*)(lbr + 16384 + kb * 512);
        bf16x8 br1 = *(const bf16x8*)(lbr + (kb + 1) * 512);
        bf16x8 bu1 = *(const bf16x8*)(lbr + 16384 + (kb + 1) * 512);
        ar0 = __builtin_amdgcn_mfma_f32_16x16x32_bf16(af[kb], br0, ar0, 0, 0, 0);
        au0 = __builtin_amdgcn_mfma_f32_16x16x32_bf16(af[kb], bu0, au0, 0, 0, 0);
        ar1 = __builtin_amdgcn_mfma_f32_16x16x32_bf16(af[kb + 1], br1, ar1, 0, 0, 0);
        au1 = __builtin_amdgcn_mfma_f32_16x16x32_bf16(af[kb + 1], bu1, au1, 0, 0, 0);
      }
      f32x4 accr = ar0 + ar1;
      f32x4 accu = au0 + au1;

#pragma unroll
      for (int r = 0; r < 4; r++) {
        float R = sigmoidf_(accr[r] + xr[r]);
        store_bf16_sc1(xaddr[r], f2bf(R * Sreg[r]));  // A2 overlay, write-through
        Ureg[r] = sigmoidf_(accu[r] + xu[r]);
      }
    }
    // barrier A: A2 must be LLC-visible to all WGs
    asm volatile("s_waitcnt vmcnt(0)" ::: "memory");
    __syncthreads();
    phase++;
    if (tid == 0)
      __hip_atomic_fetch_add(bar, 1u, __ATOMIC_RELAXED, __HIP_MEMORY_SCOPE_AGENT);
    {
      unsigned target = phase * (unsigned)NWG_SCAN;
      while (__hip_atomic_load(bar, __ATOMIC_RELAXED, __HIP_MEMORY_SCOPE_AGENT) < target)
        __builtin_amdgcn_s_sleep(1);
      asm volatile("" ::: "memory");  // compiler fence: no loads hoisted above spin
    }

    // ================= pass2: Hc GEMM + state update =================
    {
      const u16* a2base = A2 + (size_t)(rt * 16 + nl) * 3072 + bb * 8;  // overlay rows
      bf16x8 af[32];
#pragma unroll
      for (int kb = 0; kb < 32; kb++) af[kb] = *(const bf16x8*)(a2base + kb * 32);

      float xh[4];
#pragma unroll
      for (int r = 0; r < 4; r++) {
        int b_ = rt * 16 + quad * 4 + r;
        xh[r] = bf2f(Xproj[(size_t)(t * 64 + b_) * 3072 + 2048 + j]);
      }

      f32x4 ah0 = (f32x4){0.f, 0.f, 0.f, 0.f}, ah1 = ah0;
      const u16* lbh = &lds[32768 + (nl * 4 + slot) * 8];
#pragma unroll
      for (int kb = 0; kb < 32; kb += 2) {
        bf16x8 bh0 = *(const bf16x8*)(lbh + kb * 512);
        bf16x8 bh1 = *(const bf16x8*)(lbh + (kb + 1) * 512);
        ah0 = __builtin_amdgcn_mfma_f32_16x16x32_bf16(af[kb], bh0, ah0, 0, 0, 0);
        ah1 = __builtin_amdgcn_mfma_f32_16x16x32_bf16(af[kb + 1], bh1, ah1, 0, 0, 0);
      }
      f32x4 acch = ah0 + ah1;

      u16* SBn = SB + (size_t)(t + 1) * BATCH * HID;
#pragma unroll
      for (int r = 0; r < 4; r++) {
        int b_ = rt * 16 + quad * 4 + r;
        float hc = fast_tanhf(acch[r] + xh[r]);
        float snew = Ureg[r] * Sreg[r] + (1.f - Ureg[r]) * hc;
        Sreg[r] = snew;  // carried into next step's pass1 (same (b_,j) mapping)
        store_bf16_sc1(SBn + (size_t)b_ * HID + j, f2bf(snew));
      }
    }
    // barrier B: SB[t+1] must be LLC-visible; fp32 out_states stores are
    // issued AFTER arrival so their ack overlaps the spin.
    asm volatile("s_waitcnt vmcnt(0)" ::: "memory");
    __syncthreads();
    phase++;
    if (tid == 0)
      __hip_atomic_fetch_add(bar, 1u, __ATOMIC_RELAXED, __HIP_MEMORY_SCOPE_AGENT);
#pragma unroll
    for (int r = 0; r < 4; r++) {
      int b_ = rt * 16 + quad * 4 + r;
      float* p = out_states + (size_t)(t * 64 + b_) * HID + j;
      float v = Sreg[r];
      asm volatile("global_store_dword %0, %1, off" :: "v"(p), "v"(v) : "memory");
    }
    {
      unsigned target = phase * (unsigned)NWG_SCAN;
      while (__hip_atomic_load(bar, __ATOMIC_RELAXED, __HIP_MEMORY_SCOPE_AGENT) < target)
        __builtin_amdgcn_s_sleep(1);
      asm volatile("" ::: "memory");
    }
  }
}

// ---------------------------------------------------------------------------
extern "C" void kernel_launch(void* const* d_in, const int* in_sizes, int n_in,
                              void* d_out, int out_size, void* d_ws, size_t ws_size,
                              hipStream_t stream) {
  const float* X    = (const float*)d_in[0];
  const float* W_xr = (const float*)d_in[1];
  const float* W_xu = (const float*)d_in[2];
  const float* W_xh = (const float*)d_in[3];
  const float* W_hr = (const float*)d_in[4];
  const float* W_hu = (const float*)d_in[5];
  const float* W_hh = (const float*)d_in[6];
  const float* b_r  = (const float*)d_in[7];
  const float* b_u  = (const float*)d_in[8];
  const float* b_h  = (const float*)d_in[9];
  const float* W_hq = (const float*)d_in[10];
  const float* b_q  = (const float*)d_in[11];

  char* ws = (char*)d_ws;
  size_t off = 0;
  auto alloc = [&](size_t bytes) {
    char* p = ws + off;
    off = (off + bytes + 255) & ~(size_t)255;
    return p;
  };
  u16*      WxT   = (u16*)alloc(3072ull * 1024 * 2);        // B^T for phase1
  u16*      WhqT  = (u16*)alloc(1024ull * 1024 * 2);        // B^T for phase3
  float*    bias3 = (float*)alloc(3072ull * 4);
  u16*      Xproj = (u16*)alloc(32768ull * 3072 * 2);       // [T*B][3H] bf16
  u16*      SB    = (u16*)alloc(513ull * BATCH * HID * 2);  // [T+1][B][H] bf16
  unsigned* bar   = (unsigned*)alloc(256);

  hipMemsetAsync(SB, 0, (size_t)BATCH * HID * 2, stream);  // state_0 = 0
  hipMemsetAsync(bar, 0, 4, stream);

  dim3 tb(32, 8);
  dim3 tg(32, 32);
  transpose_cast<<<tg, tb, 0, stream>>>(W_xr, WxT);
  transpose_cast<<<tg, tb, 0, stream>>>(W_xu, WxT + 1024ull * 1024);
  transpose_cast<<<tg, tb, 0, stream>>>(W_xh, WxT + 2048ull * 1024);
  transpose_cast<<<tg, tb, 0, stream>>>(W_hq, WhqT);
  concat_bias<<<12, 256, 0, stream>>>(b_r, b_u, b_h, bias3);

  // Phase 1: Xproj = X @ [W_xr|W_xu|W_xh] + bias3   (bf16 out)
  gemm_bt<1, 1><<<dim3(256, 24), 256, 0, stream>>>(X, WxT, bias3, Xproj, 32768, 3072, 1024);

  // Phase 2: recurrent scan (persistent, fence-free grid barrier, 64 WGs)
  float* out_states = (float*)d_out + 33554432ull;  // after outputs [T*B*O]
  gru_scan<<<NWG_SCAN, 256, 0, stream>>>(W_hr, W_hu, W_hh, Xproj, SB, out_states, bar);

  // Phase 3: outputs = states @ W_hq + b_q   (fp32 out to d_out[0:T*B*O])
  gemm_bt<0, 0><<<dim3(256, 8), 256, 0, stream>>>(SB + (size_t)BATCH * HID, WhqT, b_q,
                                                  d_out, 32768, 1024, 1024);
}

// Round 2
// 6743.364 us; speedup vs baseline: 1.2594x; 1.2594x over previous
//
#include <hip/hip_runtime.h>
#include <stdint.h>

typedef unsigned short u16;
typedef __attribute__((ext_vector_type(8))) short bf16x8;
typedef __attribute__((ext_vector_type(4))) float f32x4;

#define T_STEPS 512
#define BATCH   64
#define HID     1024
#define NWG_SCAN 64

__device__ __forceinline__ u16 f2bf(float f) {
  union { float f; uint32_t u; } v; v.f = f;
  uint32_t r = (v.u + 0x7fffu + ((v.u >> 16) & 1u)) >> 16;  // RNE
  return (u16)r;
}
__device__ __forceinline__ float bf2f(u16 h) {
  union { uint32_t u; float f; } v; v.u = ((uint32_t)h) << 16;
  return v.f;
}
__device__ __forceinline__ float sigmoidf_(float x) {
  return 1.0f / (1.0f + __expf(-x));
}
// fast tanh via exp2-based __expf; clamped so e^{2x} can't overflow.
// bf16 state quantization (~4e-3 rel) dominates the ~1e-7 approx error.
__device__ __forceinline__ float fast_tanhf(float x) {
  float xc = fminf(15.f, fmaxf(-15.f, x));
  float e = __expf(2.f * xc);
  return (e - 1.f) / (e + 1.f);
}

// write-through store (sc1): visible at LLC once vmcnt acks -> no buffer_wbl2
// needed at the grid barrier. Local XCD L2 stays coherent with its own store.
__device__ __forceinline__ void store_bf16_sc1(u16* p, u16 v) {
  uint32_t vv = v;
  asm volatile("global_store_short %0, %1, off sc1" :: "v"(p), "v"(vv) : "memory");
}

// ---------------------------------------------------------------------------
// Transpose + cast: dst[n][k] = bf16(src[k][n]), 1024x1024
// ---------------------------------------------------------------------------
__global__ __launch_bounds__(256) void transpose_cast(const float* __restrict__ src,
                                                      u16* __restrict__ dst) {
  __shared__ float tile[32][33];
  int bx = blockIdx.x * 32;  // k block (src row)
  int by = blockIdx.y * 32;  // n block (src col)
  for (int i = threadIdx.y; i < 32; i += 8)
    tile[i][threadIdx.x] = src[(size_t)(bx + i) * 1024 + by + threadIdx.x];
  __syncthreads();
  for (int i = threadIdx.y; i < 32; i += 8)
    dst[(size_t)(by + i) * 1024 + bx + threadIdx.x] = f2bf(tile[threadIdx.x][i]);
}

// bias3 = concat(b_r, b_u, b_h)
__global__ void concat_bias(const float* __restrict__ br, const float* __restrict__ bu,
                            const float* __restrict__ bh, float* __restrict__ b3) {
  int i = blockIdx.x * blockDim.x + threadIdx.x;  // 0..3071
  float v = (i < 1024) ? br[i] : (i < 2048 ? bu[i - 1024] : bh[i - 2048]);
  b3[i] = v;
}

// ---------------------------------------------------------------------------
// GEMM: C[M,N] = A[M,K] @ B[K,N] + bias, B given transposed (BT[N][K]).
// 128x128 tile, BK=32, 256 thr, mfma 16x16x32 bf16, XOR-swizzled LDS.
// ---------------------------------------------------------------------------
template <int A_F32, int OUT_BF16>
__global__ __launch_bounds__(256) void gemm_bt(const void* __restrict__ Av,
                                               const u16* __restrict__ BT,
                                               const float* __restrict__ bias,
                                               void* __restrict__ Cv,
                                               int M, int N, int K) {
  __shared__ u16 Asm[4096];
  __shared__ u16 Bsm[4096];
  const int tid = threadIdx.x;
  const int lane = tid & 63;
  const int wv = tid >> 6;
  const int wm = wv >> 1, wn = wv & 1;
  const int m0 = blockIdx.x * 128;
  const int n0 = blockIdx.y * 128;

  f32x4 acc[4][4];
#pragma unroll
  for (int i = 0; i < 4; i++)
#pragma unroll
    for (int j = 0; j < 4; j++) acc[i][j] = (f32x4){0.f, 0.f, 0.f, 0.f};

  for (int kt = 0; kt < K; kt += 32) {
    __syncthreads();
#pragma unroll
    for (int i = 0; i < 2; i++) {
      int q = tid + i * 256;
      int m = q >> 2, s = q & 3;
      int bb = s ^ ((m & 3) ^ ((m >> 2) & 3));
      if (A_F32) {
        const float* srcp = (const float*)Av + (size_t)(m0 + m) * K + kt + bb * 8;
        bf16x8 o;
#pragma unroll
        for (int e = 0; e < 8; e++) o[e] = (short)f2bf(srcp[e]);
        *(bf16x8*)&Asm[q * 8] = o;
      } else {
        const u16* srcp = (const u16*)Av + (size_t)(m0 + m) * K + kt + bb * 8;
        *(bf16x8*)&Asm[q * 8] = *(const bf16x8*)srcp;
      }
      const u16* srcb = BT + (size_t)(n0 + m) * K + kt + bb * 8;
      *(bf16x8*)&Bsm[q * 8] = *(const bf16x8*)srcb;
    }
    __syncthreads();

    bf16x8 af[4], bfr[4];
    int bb = lane >> 4;
#pragma unroll
    for (int mt = 0; mt < 4; mt++) {
      int m = wm * 64 + mt * 16 + (lane & 15);
      int s = bb ^ ((m & 3) ^ ((m >> 2) & 3));
      af[mt] = *(const bf16x8*)&Asm[m * 32 + s * 8];
    }
#pragma unroll
    for (int nt = 0; nt < 4; nt++) {
      int n = wn * 64 + nt * 16 + (lane & 15);
      int s = bb ^ ((n & 3) ^ ((n >> 2) & 3));
      bfr[nt] = *(const bf16x8*)&Bsm[n * 32 + s * 8];
    }
#pragma unroll
    for (int mt = 0; mt < 4; mt++)
#pragma unroll
      for (int nt = 0; nt < 4; nt++)
        acc[mt][nt] = __builtin_amdgcn_mfma_f32_16x16x32_bf16(af[mt], bfr[nt], acc[mt][nt], 0, 0, 0);
  }

#pragma unroll
  for (int nt = 0; nt < 4; nt++) {
    int col = n0 + wn * 64 + nt * 16 + (lane & 15);
    float bv = bias[col];
#pragma unroll
    for (int mt = 0; mt < 4; mt++) {
#pragma unroll
      for (int r = 0; r < 4; r++) {
        int row = m0 + wm * 64 + mt * 16 + (lane >> 4) * 4 + r;
        float v = acc[mt][nt][r] + bv;
        if (OUT_BF16)
          ((u16*)Cv)[(size_t)row * N + col] = f2bf(v);
        else
          ((float*)Cv)[(size_t)row * N + col] = v;
      }
    }
  }
}

// ---------------------------------------------------------------------------
// Persistent GRU scan, 64 WGs x 256 thr (1 WG/CU, 96KB LDS).
// Each WG owns cols j = wg*16..wg*16+15 of ALL THREE recurrent matrices.
// pass1: R-gate + U-gate GEMMs (shared A-fragments from SB[t], loaded once).
//        Writes A2 = bf16(R*s_prev) with sc1 stores OVERLAYED onto Xproj's
//        r-region for step t. U and s_prev stay in REGISTERS.
// pass2: Hc GEMM over A2-overlay + state update; SB[t+1] via sc1.
//
// Grid barrier = EPOCH FLAG ARRAY (no atomics):
//   arrive: vmcnt(0) drain -> syncthreads -> tid0 plain agent-store of phase
//           to flags[wg] (64 flags in 4 cachelines; stores don't serialize
//           like RMW atomics under the spin-read storm).
//   wait:   wave0 only: lanes 0..63 vector-load flags[lane] (one instr, 4
//           coalesced line requests), __all(v >= phase). Waves 1-3 park at
//           the trailing __syncthreads. Detection ~= one LLC round trip.
// Barrier-independent Xproj scalars are prefetched BEFORE each spin so their
// latency hides under the wait.
// ---------------------------------------------------------------------------
__global__ __launch_bounds__(256, 1) void gru_scan(const float* __restrict__ W_hr,
                                                   const float* __restrict__ W_hu,
                                                   const float* __restrict__ W_hh,
                                                   u16* __restrict__ Xproj,        // [T*B][3072] bf16 (r-region mutated)
                                                   u16* __restrict__ SB,           // [T+1][B][H] bf16
                                                   float* __restrict__ out_states, // [T*B][H] fp32
                                                   unsigned* __restrict__ flags) { // [64] epoch flags
  __shared__ u16 lds[49152];  // 96KB: [0:16K)=W_hr slice, [16K:32K)=W_hu, [32K:48K)=W_hh
  const int tid = threadIdx.x;
  const int lane = tid & 63;
  const int wv = tid >> 6;
  const int wg = blockIdx.x;  // 0..63

  // ---- one-time LDS weight fill: 1024x16 slice of each matrix, swizzled ----
  {
    const int cbase = wg * 16;
#pragma unroll
    for (int s = 0; s < 3; s++) {
      const float* Wsrc = (s == 0) ? W_hr : (s == 1) ? W_hu : W_hh;
      for (int idx = tid; idx < 16384; idx += 256) {
        int kin = idx & 31, nl_ = (idx >> 5) & 15, kb = idx >> 9;
        float v = Wsrc[(size_t)(kb * 32 + kin) * 1024 + cbase + nl_];
        int slot_ = (kin >> 3) ^ (nl_ & 3) ^ ((nl_ >> 2) & 3);
        lds[s * 16384 + ((kb * 16 + nl_) * 4 + slot_) * 8 + (kin & 7)] = f2bf(v);
      }
    }
  }
  __syncthreads();

  unsigned phase = 0;
  const int bb = lane >> 4;
  const int nl = lane & 15;
  const int quad = lane >> 4;
  const int slot = bb ^ ((nl & 3) ^ ((nl >> 2) & 3));
  const int rt = wv;            // wave's 16-row block of the 64 batch rows
  const int j = wg * 16 + nl;   // this thread's output column

  float Ureg[4];
  float Sreg[4] = {0.f, 0.f, 0.f, 0.f};  // s_t(b_,j), carried across steps; s_0 = 0

  // prefetched pass1 scalars (xr from A2 pre-overlay, xu from u-region)
  float xr[4], xu[4];
  u16* xaddr[4];
  {
    u16* A2_0 = Xproj;  // t = 0
#pragma unroll
    for (int r = 0; r < 4; r++) {
      int b_ = rt * 16 + quad * 4 + r;
      xaddr[r] = A2_0 + (size_t)b_ * 3072 + j;
      xr[r] = bf2f(*xaddr[r]);
      xu[r] = bf2f(Xproj[(size_t)b_ * 3072 + 1024 + j]);
    }
  }

  for (int t = 0; t < T_STEPS; t++) {
    const u16* SBt = SB + (size_t)t * BATCH * HID;
    u16* A2 = Xproj + (size_t)t * 64 * 3072;  // r-region overlay, row stride 3072

    // ================= pass1: R and U gate GEMMs =================
    {
      // A-fragments: full state rows (loaded ONCE, used for both gates)
      const u16* abase = SBt + (size_t)(rt * 16 + nl) * HID + bb * 8;
      bf16x8 af[32];
#pragma unroll
      for (int kb = 0; kb < 32; kb++) af[kb] = *(const bf16x8*)(abase + kb * 32);

      // 64 MFMAs in 4 independent chains (r0,u0,r1,u1)
      f32x4 ar0 = (f32x4){0.f, 0.f, 0.f, 0.f}, ar1 = ar0, au0 = ar0, au1 = ar0;
      const u16* lbr = &lds[(nl * 4 + slot) * 8];
#pragma unroll
      for (int kb = 0; kb < 32; kb += 2) {
        bf16x8 br0 = *(const bf16x8*)(lbr + kb * 512);
        bf16x8 bu0 = *(const bf16x8*)(lbr + 16384 + kb * 512);
        bf16x8 br1 = *(const bf16x8*)(lbr + (kb + 1) * 512);
        bf16x8 bu1 = *(const bf16x8*)(lbr + 16384 + (kb + 1) * 512);
        ar0 = __builtin_amdgcn_mfma_f32_16x16x32_bf16(af[kb], br0, ar0, 0, 0, 0);
        au0 = __builtin_amdgcn_mfma_f32_16x16x32_bf16(af[kb], bu0, au0, 0, 0, 0);
        ar1 = __builtin_amdgcn_mfma_f32_16x16x32_bf16(af[kb + 1], br1, ar1, 0, 0, 0);
        au1 = __builtin_amdgcn_mfma_f32_16x16x32_bf16(af[kb + 1], bu1, au1, 0, 0, 0);
      }
      f32x4 accr = ar0 + ar1;
      f32x4 accu = au0 + au1;

#pragma unroll
      for (int r = 0; r < 4; r++) {
        float R = sigmoidf_(accr[r] + xr[r]);
        store_bf16_sc1(xaddr[r], f2bf(R * Sreg[r]));  // A2 overlay, write-through
        Ureg[r] = sigmoidf_(accu[r] + xu[r]);
      }
    }

    // ---- barrier A: A2 must be LLC-visible to all WGs ----
    asm volatile("s_waitcnt vmcnt(0)" ::: "memory");
    __syncthreads();
    phase++;
    if (tid == 0)
      __hip_atomic_store(&flags[wg], phase, __ATOMIC_RELAXED, __HIP_MEMORY_SCOPE_AGENT);
    // prefetch pass2's xh (barrier-independent) so it loads under the spin
    float xh[4];
#pragma unroll
    for (int r = 0; r < 4; r++) {
      int b_ = rt * 16 + quad * 4 + r;
      xh[r] = bf2f(Xproj[(size_t)(t * 64 + b_) * 3072 + 2048 + j]);
    }
    if (wv == 0) {
      while (true) {
        unsigned v = __hip_atomic_load(&flags[lane], __ATOMIC_RELAXED, __HIP_MEMORY_SCOPE_AGENT);
        if (__all((int)(v >= phase))) break;
        __builtin_amdgcn_s_sleep(1);
      }
    }
    __syncthreads();
    asm volatile("" ::: "memory");  // no loads hoisted above the wait

    // ================= pass2: Hc GEMM + state update =================
    {
      const u16* a2base = A2 + (size_t)(rt * 16 + nl) * 3072 + bb * 8;  // overlay rows
      bf16x8 af[32];
#pragma unroll
      for (int kb = 0; kb < 32; kb++) af[kb] = *(const bf16x8*)(a2base + kb * 32);

      f32x4 ah0 = (f32x4){0.f, 0.f, 0.f, 0.f}, ah1 = ah0;
      const u16* lbh = &lds[32768 + (nl * 4 + slot) * 8];
#pragma unroll
      for (int kb = 0; kb < 32; kb += 2) {
        bf16x8 bh0 = *(const bf16x8*)(lbh + kb * 512);
        bf16x8 bh1 = *(const bf16x8*)(lbh + (kb + 1) * 512);
        ah0 = __builtin_amdgcn_mfma_f32_16x16x32_bf16(af[kb], bh0, ah0, 0, 0, 0);
        ah1 = __builtin_amdgcn_mfma_f32_16x16x32_bf16(af[kb + 1], bh1, ah1, 0, 0, 0);
      }
      f32x4 acch = ah0 + ah1;

      u16* SBn = SB + (size_t)(t + 1) * BATCH * HID;
#pragma unroll
      for (int r = 0; r < 4; r++) {
        int b_ = rt * 16 + quad * 4 + r;
        float hc = fast_tanhf(acch[r] + xh[r]);
        float snew = Ureg[r] * Sreg[r] + (1.f - Ureg[r]) * hc;
        Sreg[r] = snew;  // carried into next step's pass1 (same (b_,j) mapping)
        store_bf16_sc1(SBn + (size_t)b_ * HID + j, f2bf(snew));
      }
    }

    // ---- barrier B: SB[t+1] must be LLC-visible ----
    asm volatile("s_waitcnt vmcnt(0)" ::: "memory");
    __syncthreads();
    phase++;
    if (tid == 0)
      __hip_atomic_store(&flags[wg], phase, __ATOMIC_RELAXED, __HIP_MEMORY_SCOPE_AGENT);
    // off-critical-path work under the spin: fp32 out_states stores + next
    // step's pass1 scalar prefetch (both barrier-independent)
#pragma unroll
    for (int r = 0; r < 4; r++) {
      int b_ = rt * 16 + quad * 4 + r;
      float* p = out_states + (size_t)(t * 64 + b_) * HID + j;
      float v = Sreg[r];
      asm volatile("global_store_dword %0, %1, off" :: "v"(p), "v"(v) : "memory");
    }
    if (t + 1 < T_STEPS) {
      u16* A2n = Xproj + (size_t)(t + 1) * 64 * 3072;
#pragma unroll
      for (int r = 0; r < 4; r++) {
        int b_ = rt * 16 + quad * 4 + r;
        xaddr[r] = A2n + (size_t)b_ * 3072 + j;
        xr[r] = bf2f(*xaddr[r]);
        xu[r] = bf2f(Xproj[(size_t)((t + 1) * 64 + b_) * 3072 + 1024 + j]);
      }
    }
    if (wv == 0) {
      while (true) {
        unsigned v = __hip_atomic_load(&flags[lane], __ATOMIC_RELAXED, __HIP_MEMORY_SCOPE_AGENT);
        if (__all((int)(v >= phase))) break;
        __builtin_amdgcn_s_sleep(1);
      }
    }
    __syncthreads();
    asm volatile("" ::: "memory");
  }
}

// ---------------------------------------------------------------------------
extern "C" void kernel_launch(void* const* d_in, const int* in_sizes, int n_in,
                              void* d_out, int out_size, void* d_ws, size_t ws_size,
                              hipStream_t stream) {
  const float* X    = (const float*)d_in[0];
  const float* W_xr = (const float*)d_in[1];
  const float* W_xu = (const float*)d_in[2];
  const float* W_xh = (const float*)d_in[3];
  const float* W_hr = (const float*)d_in[4];
  const float* W_hu = (const float*)d_in[5];
  const float* W_hh = (const float*)d_in[6];
  const float* b_r  = (const float*)d_in[7];
  const float* b_u  = (const float*)d_in[8];
  const float* b_h  = (const float*)d_in[9];
  const float* W_hq = (const float*)d_in[10];
  const float* b_q  = (const float*)d_in[11];

  char* ws = (char*)d_ws;
  size_t off = 0;
  auto alloc = [&](size_t bytes) {
    char* p = ws + off;
    off = (off + bytes + 255) & ~(size_t)255;
    return p;
  };
  u16*      WxT   = (u16*)alloc(3072ull * 1024 * 2);        // B^T for phase1
  u16*      WhqT  = (u16*)alloc(1024ull * 1024 * 2);        // B^T for phase3
  float*    bias3 = (float*)alloc(3072ull * 4);
  u16*      Xproj = (u16*)alloc(32768ull * 3072 * 2);       // [T*B][3H] bf16
  u16*      SB    = (u16*)alloc(513ull * BATCH * HID * 2);  // [T+1][B][H] bf16
  unsigned* flags = (unsigned*)alloc(256);                  // 64 epoch flags

  hipMemsetAsync(SB, 0, (size_t)BATCH * HID * 2, stream);  // state_0 = 0
  hipMemsetAsync(flags, 0, 256, stream);

  dim3 tb(32, 8);
  dim3 tg(32, 32);
  transpose_cast<<<tg, tb, 0, stream>>>(W_xr, WxT);
  transpose_cast<<<tg, tb, 0, stream>>>(W_xu, WxT + 1024ull * 1024);
  transpose_cast<<<tg, tb, 0, stream>>>(W_xh, WxT + 2048ull * 1024);
  transpose_cast<<<tg, tb, 0, stream>>>(W_hq, WhqT);
  concat_bias<<<12, 256, 0, stream>>>(b_r, b_u, b_h, bias3);

  // Phase 1: Xproj = X @ [W_xr|W_xu|W_xh] + bias3   (bf16 out)
  gemm_bt<1, 1><<<dim3(256, 24), 256, 0, stream>>>(X, WxT, bias3, Xproj, 32768, 3072, 1024);

  // Phase 2: recurrent scan (persistent, flag-array grid barrier, 64 WGs)
  float* out_states = (float*)d_out + 33554432ull;  // after outputs [T*B*O]
  gru_scan<<<NWG_SCAN, 256, 0, stream>>>(W_hr, W_hu, W_hh, Xproj, SB, out_states, flags);

  // Phase 3: outputs = states @ W_hq + b_q   (fp32 out to d_out[0:T*B*O])
  gemm_bt<0, 0><<<dim3(256, 8), 256, 0, stream>>>(SB + (size_t)BATCH * HID, WhqT, b_q,
                                                  d_out, 32768, 1024, 1024);
}